// Round 5
// baseline (4894.006 us; speedup 1.0000x reference)
//
#include <hip/hip_runtime.h>
#include <stdint.h>

// ---------------------------------------------------------------------------
// LSTMSingle v7:
//  K2 recurrence with SELF-ORGANIZING same-XCD groups + EMPIRICAL transport
//  probe. 256 wgs rendezvous via IC atomics (all co-resident at 1+/CU);
//  if every XCD has >=16 wgs, group g = first 16 arrivals on XCD g
//  (co-location by construction). Each group then PROBES the sc0/L2
//  transport (bounded 32-round handshake, result AND-reduced via IC):
//  pass -> tagged-word exchange through per-XCD L2 (sc0);
//  fail -> agent-scope IC path (= v4 behavior, known 1650us).
//  Any deficit in XCD counts -> uniform static fallback (IC path).
//  Per-step rescue (threshold 256 rounds, republish via IC) kept as
//  insurance: no placement/probe outcome can hang or corrupt.
//  K0/Kcvt/K1/K3 unchanged.
// ---------------------------------------------------------------------------

#define NB   128
#define LMAX 512
#define HD   512
#define G4   2048
#define NV   50000

// workspace layout (bytes)
#define H0C_OFF     0                            // compact final h [128][512] f16
#define T0_OFF      131072                       // tagged h parity0: 128*256*8
#define T1_OFF      393216                       // tagged h parity1
#define C_OFF       655360                       // c state f32 128*512*4
#define RDV_OFF     917504                       // rendezvous: 8 ci * 512 u32
#define EMB16_OFF   933888
#define EMB16_BYTES (NV * HD * 2)                // 51,200,000
#define WIH16_OFF   (EMB16_OFF + EMB16_BYTES)
#define WIH16_BYTES (G4 * HD * 2)                // 2,097,152
#define XP_OFF      (WIH16_OFF + WIH16_BYTES)
#define INIT_W4     58368                        // 933888/16

#define PROBE_MAGIC 0x5AD0BEEF5AD0BEEFull

typedef _Float16 f16;
typedef _Float16 half8  __attribute__((ext_vector_type(8)));
typedef float    float4v __attribute__((ext_vector_type(4)));
typedef uint32_t u32;
typedef unsigned long long u64;
typedef uint32_t u32x4 __attribute__((ext_vector_type(4)));

__device__ __forceinline__ half8 cvt8(const float* p) {
  float4v a = *(const float4v*)p;
  float4v b = *(const float4v*)(p + 4);
  half8 r;
  r[0] = (f16)a[0]; r[1] = (f16)a[1]; r[2] = (f16)a[2]; r[3] = (f16)a[3];
  r[4] = (f16)b[0]; r[5] = (f16)b[1]; r[6] = (f16)b[2]; r[7] = (f16)b[3];
  return r;
}
__device__ __forceinline__ float sigmoidf_(float x) { return 1.0f / (1.0f + __expf(-x)); }
__device__ __forceinline__ float tanhf_(float x)    { return 1.0f - 2.0f / (1.0f + __expf(2.0f * x)); }

// raw workgroup barrier: LDS visibility only, does NOT drain vmcnt
__device__ __forceinline__ void barx() {
  __builtin_amdgcn_sched_barrier(0);
  __builtin_amdgcn_s_waitcnt(0xC07F);   // lgkmcnt(0), vmcnt/expcnt untouched
  __builtin_amdgcn_s_barrier();
  __builtin_amdgcn_sched_barrier(0);
}

// issue 16 tagged-word loads, stride 256 u64, NO wait (caller waits vmcnt(0))
__device__ __forceinline__ void ld16f(u64* a, const u64* base) {   // same-XCD: L2 meet
  #pragma unroll
  for (int r = 0; r < 16; ++r)
    asm volatile("global_load_dwordx2 %0, %1, off sc0"
                 : "=v"(a[r]) : "v"(base + (size_t)r * 256) : "memory");
}
__device__ __forceinline__ void ld16s(u64* a, const u64* base) {   // cross-XCD: IC meet
  #pragma unroll
  for (int r = 0; r < 16; ++r)
    a[r] = __hip_atomic_load(base + (size_t)r * 256,
                             __ATOMIC_RELAXED, __HIP_MEMORY_SCOPE_AGENT);
}

// ---------------------------------------------------------------- K0: init
extern "C" __global__ void k0_init(u32x4* ws4) {
  int idx = blockIdx.x * 256 + threadIdx.x;
  u32x4 z = {0u, 0u, 0u, 0u};
  if (idx < INIT_W4) ws4[idx] = z;
}

// ------------------------------------------------------------- Kcvt: f32->f16
extern "C" __global__ void __launch_bounds__(256)
k_cvt(const float* __restrict__ src, f16* __restrict__ dst, int n8) {
  int i = blockIdx.x * 256 + threadIdx.x;
  if (i >= n8) return;
  ((half8*)dst)[i] = cvt8(src + (size_t)i * 8);
}

// -------------------------------------------------------------- K1: x_proj
extern "C" __global__ void __launch_bounds__(256)
k1_xproj(const int* __restrict__ tokens, const int* __restrict__ lengths,
         const f16* __restrict__ emb16, const f16* __restrict__ wih16,
         const float* __restrict__ bih, const float* __restrict__ bhh,
         f16* __restrict__ xp, int t0c, int TC) {
  int b  = blockIdx.x;
  int mt = blockIdx.y;
  int nt = blockIdx.z;
  int len = lengths[b];
  int t0 = t0c + mt * 64;
  if (t0 >= len) return;

  __shared__ f16 As[64 * 512];                // 64 KB, XOR-swizzled granules
  int tid = threadIdx.x;

  #pragma unroll
  for (int it = 0; it < 16; ++it) {
    int gl = tid + 256 * it;
    int row = gl >> 6, gi = gl & 63;
    int tok = tokens[b * LMAX + t0 + row];
    half8 v = *(const half8*)(emb16 + (size_t)tok * HD + gi * 8);
    *(half8*)&As[row * 512 + ((gi ^ (row & 7)) * 8)] = v;
  }
  __syncthreads();

  int wave = tid >> 6, lane = tid & 63;
  int quad = lane >> 4, l15 = lane & 15;
  int col0 = nt * 128 + wave * 32;

  float4v acc[4][2] = {};
  for (int c = 0; c < 16; ++c) {
    half8 b0 = *(const half8*)(wih16 + (size_t)(col0 + l15) * HD + c * 32 + quad * 8);
    half8 b1 = *(const half8*)(wih16 + (size_t)(col0 + 16 + l15) * HD + c * 32 + quad * 8);
    #pragma unroll
    for (int mm = 0; mm < 4; ++mm) {
      int row = mm * 16 + l15;
      half8 a = *(const half8*)&As[row * 512 + (((c * 4 + quad) ^ (row & 7)) * 8)];
      acc[mm][0] = __builtin_amdgcn_mfma_f32_16x16x32_f16(a, b0, acc[mm][0], 0, 0, 0);
      acc[mm][1] = __builtin_amdgcn_mfma_f32_16x16x32_f16(a, b1, acc[mm][1], 0, 0, 0);
    }
  }

  #pragma unroll
  for (int q = 0; q < 2; ++q) {
    int gcol = col0 + q * 16 + l15;
    float bias = bih[gcol] + bhh[gcol];
    #pragma unroll
    for (int mm = 0; mm < 4; ++mm) {
      #pragma unroll
      for (int j = 0; j < 4; ++j) {
        int t = t0 + mm * 16 + quad * 4 + j;
        if (t < len)
          xp[((size_t)b * TC + (t - t0c)) * G4 + gcol] = (f16)(acc[mm][q][j] + bias);
      }
    }
  }
}

// ---------------------------------------------------------- K2: recurrence
// 256 wgs launched; 128 become members (16 per group), rest exit.
// rdv area per ci (512 u32): [0]=total, [1..8]=cnt per XCD,
// [16..143]=pub flags, u64 probe words at +256 u32 (1KB, 8B aligned).
extern "C" __global__ void __launch_bounds__(256, 1)
k2_lstm(const int* __restrict__ lengths, const float* __restrict__ Whh,
        const f16* __restrict__ xp, u64* __restrict__ tb0, u64* __restrict__ tb1,
        f16* __restrict__ h0c, float* __restrict__ cbuf, u32* __restrict__ rdv,
        int ci, int t0c, int TC) {
  int tid = threadIdx.x;
  u32* area = rdv + ci * 512;

  __shared__ u32 shGrp, shMemb, shCand, shAct, shProbe;

  // ---- rendezvous: self-organize groups by actual XCD placement ----
  if (tid == 0) {
    u32 x;
    asm volatile("s_getreg_b32 %0, hwreg(HW_REG_XCC_ID)" : "=s"(x));
    x &= 7u;
    u32 r = __hip_atomic_fetch_add(area + 1 + x, 1u,
                                   __ATOMIC_RELAXED, __HIP_MEMORY_SCOPE_AGENT);
    u32 R = __hip_atomic_fetch_add(area + 0, 1u,
                                   __ATOMIC_RELEASE, __HIP_MEMORY_SCOPE_AGENT);
    while (__hip_atomic_load(area + 0, __ATOMIC_ACQUIRE,
                             __HIP_MEMORY_SCOPE_AGENT) < 256u)
      __builtin_amdgcn_s_sleep(8);
    u32 ok = 1;
    #pragma unroll
    for (int i = 0; i < 8; ++i) {
      u32 c = __hip_atomic_load(area + 1 + i, __ATOMIC_RELAXED,
                                __HIP_MEMORY_SCOPE_AGENT);
      ok &= (c >= 16u) ? 1u : 0u;
    }
    u32 grp = 0, memb = 0, cand = 0, act = 0;
    if (ok) {
      if (r < 16u) { grp = x; memb = r; cand = 1; act = 1; }
    } else {
      if (R < 128u) { grp = R & 7u; memb = R >> 3; cand = 0; act = 1; }
    }
    shGrp = grp; shMemb = memb; shCand = cand; shAct = act;
  }
  __syncthreads();
  if (!shAct) return;                       // wg-uniform
  int grp = (int)shGrp, memb = (int)shMemb;
  int s0 = grp * 16;

  int gm = 0;
  for (int i = 0; i < 16; ++i) { int l = lengths[s0 + i]; gm = l > gm ? l : gm; }
  int tend = (t0c + TC < gm) ? (t0c + TC) : gm;
  if (t0c >= tend) return;                  // uniform per group (all or none)

  // ---- empirical transport probe (fast candidates only) ----
  if (shCand) {
    if (tid == 0) {
      u64* pw = (u64*)(area + 256) + grp * 16;
      u64 mg = PROBE_MAGIC;
      asm volatile("global_store_dwordx2 %0, %1, off sc0"
                   :: "v"(pw + memb), "v"(mg) : "memory");
      int seen = 0;
      for (int round = 0; round < 32; ++round) {
        u64 pv[16];
        #pragma unroll
        for (int m = 0; m < 16; ++m)
          asm volatile("global_load_dwordx2 %0, %1, off sc0"
                       : "=v"(pv[m]) : "v"(pw + m) : "memory");
        asm volatile("s_waitcnt vmcnt(0)" ::: "memory");
        __builtin_amdgcn_sched_barrier(0);
        seen = 0;
        #pragma unroll
        for (int m = 0; m < 16; ++m) seen += (pv[m] == PROBE_MAGIC) ? 1 : 0;
        if (seen == 16) break;
        __builtin_amdgcn_s_sleep(2);
      }
      u32 pok = (seen == 16) ? 2u : 1u;
      __hip_atomic_store(area + 16 + grp * 16 + memb, pok,
                         __ATOMIC_RELAXED, __HIP_MEMORY_SCOPE_AGENT);
      u32 f = 1;
      for (int m = 0; m < 16; ++m) {
        u32 v;
        do {
          v = __hip_atomic_load(area + 16 + grp * 16 + m,
                                __ATOMIC_RELAXED, __HIP_MEMORY_SCOPE_AGENT);
          if (!v) __builtin_amdgcn_s_sleep(2);
        } while (!v);
        f &= (v == 2u) ? 1u : 0u;
      }
      shProbe = f;
    }
    __syncthreads();
  }
  bool fastR = shCand && (shProbe != 0u);   // group-uniform

  __shared__ f16 Hs[16 * 512];              // 16 KB
  __shared__ float gS[16][133];             // padded: odd stride

  int wave = tid >> 6, lane = tid & 63;
  int quad = lane >> 4, l15 = lane & 15;

  // register-resident W_hh fragments: wave w <-> gate block w
  half8 wf0[16], wf1[16];
  {
    const float* r0 = Whh + (size_t)(wave * 512 + memb * 32 + l15) * HD;
    const float* r1 = r0 + (size_t)16 * HD;
    #pragma unroll
    for (int c = 0; c < 16; ++c) {
      wf0[c] = cvt8(r0 + c * 32 + quad * 8);
      wf1[c] = cvt8(r1 + c * 32 + quad * 8);
    }
  }

  // elementwise: thread owns (seq sE, 2 cols kk0..kk0+1)
  int sE = tid >> 4, kE = tid & 15, kk0 = kE * 2;
  int len = lengths[s0 + sE];
  float c0 = cbuf[(size_t)(s0 + sE) * HD + memb * 32 + kk0];
  float c1 = cbuf[(size_t)(s0 + sE) * HD + memb * 32 + kk0 + 1];

  // own tagged word + initial (frozen) h from previous chunk
  size_t wIdx = (size_t)(s0 + sE) * 256 + memb * 16 + kE;
  const u64* hin0 = (t0c & 1) ? tb1 : tb0;
  u32 hp = (u32)hin0[wIdx];

  // last two words I stored (for idempotent rescue republish)
  u64 wv_cur  = ((u64)(u32)t0c << 32) | (u64)hp;
  u64 wv_prev = wv_cur;

  // staging address components: thread tid covers col-pair tid of every seq
  int gG = tid >> 2, w4 = (tid & 3) * 2;    // granule 0..63, f16 offset

  u64 a[16];
  ld16s(a, hin0 + (size_t)s0 * 256 + tid);  // cross-launch: IC-coherent

  for (int t = t0c; t < tend; ++t) {
    const u64* tin  = (t & 1) ? tb1 : tb0;
    u64*       tout = (t & 1) ? tb0 : tb1;
    const u64* tinb = tin + (size_t)s0 * 256 + tid;
    u32 tg = (u32)t;

    // xp prefetch (covers the spin latency)
    u32 x4[4];
    {
      const f16* p = xp + ((size_t)(s0 + sE) * TC + (t - t0c)) * G4 + memb * 32 + kk0;
      x4[0] = *(const u32*)p;          x4[1] = *(const u32*)(p + 512);
      x4[2] = *(const u32*)(p + 1024); x4[3] = *(const u32*)(p + 1536);
    }

    // spin until all 16 tags == t (data+tag atomic in same u64)
    {
      int spin = 0;
      for (;;) {
        asm volatile("s_waitcnt vmcnt(0)" ::: "memory");
        __builtin_amdgcn_sched_barrier(0);
        u32 bad = 0;
        #pragma unroll
        for (int r = 0; r < 16; ++r)
          bad |= ((u32)(a[r] >> 32) != tg) ? 1u : 0u;
        if (!bad) break;
        // insurance rescue (probe-validated fast should never hit this)
        if (fastR && t != t0c && ++spin == 256) {
          fastR = false;
          __hip_atomic_store((u64*)tin + wIdx, wv_cur,
                             __ATOMIC_RELAXED, __HIP_MEMORY_SCOPE_AGENT);
          __hip_atomic_store(tout + wIdx, wv_prev,
                             __ATOMIC_RELAXED, __HIP_MEMORY_SCOPE_AGENT);
        }
        __builtin_amdgcn_s_sleep(1);
        if (fastR) ld16f(a, tinb); else ld16s(a, tinb);
      }
    }

    // stage h into LDS (XOR-swizzled granules)
    #pragma unroll
    for (int r = 0; r < 16; ++r)
      *(u32*)&Hs[r * 512 + ((gG ^ (r & 7)) << 3) + w4] = (u32)a[r];
    barx();

    // GEMM: gates = h @ Whh fragment
    float4v a0e = {}, a0o = {}, a1e = {}, a1o = {};
    #pragma unroll
    for (int c = 0; c < 16; ++c) {
      half8 av = *(const half8*)&Hs[l15 * 512 + (((c * 4 + quad) ^ (l15 & 7)) * 8)];
      if (c & 1) {
        a0o = __builtin_amdgcn_mfma_f32_16x16x32_f16(av, wf0[c], a0o, 0, 0, 0);
        a1o = __builtin_amdgcn_mfma_f32_16x16x32_f16(av, wf1[c], a1o, 0, 0, 0);
      } else {
        a0e = __builtin_amdgcn_mfma_f32_16x16x32_f16(av, wf0[c], a0e, 0, 0, 0);
        a1e = __builtin_amdgcn_mfma_f32_16x16x32_f16(av, wf1[c], a1e, 0, 0, 0);
      }
    }
    float4v g0 = a0e + a0o, g1 = a1e + a1o;
    #pragma unroll
    for (int j = 0; j < 4; ++j) {
      gS[quad * 4 + j][wave * 32 + l15]      = g0[j];
      gS[quad * 4 + j][wave * 32 + 16 + l15] = g1[j];
    }
    barx();

    // elementwise gate math (only while seq is active; frozen h re-stored)
    if (t < len) {
      union { u32 u; f16 h[2]; } xi, xf, xg, xo, hpk;
      xi.u = x4[0]; xf.u = x4[1]; xg.u = x4[2]; xo.u = x4[3];
      float i0 = sigmoidf_(gS[sE][kk0]          + (float)xi.h[0]);
      float i1 = sigmoidf_(gS[sE][kk0 + 1]      + (float)xi.h[1]);
      float f0 = sigmoidf_(gS[sE][32 + kk0]     + (float)xf.h[0]);
      float f1 = sigmoidf_(gS[sE][32 + kk0 + 1] + (float)xf.h[1]);
      float q0 = tanhf_  (gS[sE][64 + kk0]      + (float)xg.h[0]);
      float q1 = tanhf_  (gS[sE][64 + kk0 + 1]  + (float)xg.h[1]);
      float o0 = sigmoidf_(gS[sE][96 + kk0]     + (float)xo.h[0]);
      float o1 = sigmoidf_(gS[sE][96 + kk0 + 1] + (float)xo.h[1]);
      c0 = f0 * c0 + i0 * q0;
      c1 = f1 * c1 + i1 * q1;
      hpk.h[0] = (f16)(o0 * tanhf_(c0));
      hpk.h[1] = (f16)(o1 * tanhf_(c1));
      hp = hpk.u;
    }
    u64 wv = ((u64)(u32)(t + 1) << 32) | (u64)hp;
    wv_prev = wv_cur; wv_cur = wv;
    if (fastR)
      asm volatile("global_store_dwordx2 %0, %1, off sc0"
                   :: "v"(tout + wIdx), "v"(wv) : "memory");
    else
      __hip_atomic_store(tout + wIdx, wv, __ATOMIC_RELAXED, __HIP_MEMORY_SCOPE_AGENT);

    // prefetch next step's words immediately (validated by next spin)
    if (t + 1 < tend) {
      const u64* toutb = tout + (size_t)s0 * 256 + tid;
      if (fastR) ld16f(a, toutb); else ld16s(a, toutb);
    }
  }

  // persist cell state
  cbuf[(size_t)(s0 + sE) * HD + memb * 32 + kk0]     = c0;
  cbuf[(size_t)(s0 + sE) * HD + memb * 32 + kk0 + 1] = c1;

  // compact final h for K3 (frozen values correct for finished seqs)
  *(u32*)&h0c[(size_t)(s0 + sE) * HD + memb * 32 + kk0] = hp;
}

// ----------------------------------------------------------------- K3: FC
extern "C" __global__ void __launch_bounds__(256)
k3_fc(const f16* __restrict__ hT, const float* __restrict__ Wfc,
      const float* __restrict__ bfc, float* __restrict__ out) {
  int tid = threadIdx.x;
  int wave = tid >> 6, lane = tid & 63, quad = lane >> 4, l15 = lane & 15;
  int v = blockIdx.x * 64 + wave * 16 + l15;
  int vc = v < NV ? v : NV - 1;
  float4v acc[8] = {};
  for (int c = 0; c < 16; ++c) {
    half8 bfr = cvt8(Wfc + (size_t)vc * HD + c * 32 + quad * 8);
    #pragma unroll
    for (int mt = 0; mt < 8; ++mt) {
      half8 afr = *(const half8*)&hT[(size_t)(mt * 16 + l15) * HD + c * 32 + quad * 8];
      acc[mt] = __builtin_amdgcn_mfma_f32_16x16x32_f16(afr, bfr, acc[mt], 0, 0, 0);
    }
  }
  if (v < NV) {
    float bias = bfc[v];
    #pragma unroll
    for (int mt = 0; mt < 8; ++mt)
      #pragma unroll
      for (int j = 0; j < 4; ++j)
        out[(size_t)(mt * 16 + quad * 4 + j) * NV + v] = acc[mt][j] + bias;
  }
}

// ---------------------------------------------------------------- launcher
extern "C" void kernel_launch(void* const* d_in, const int* in_sizes, int n_in,
                              void* d_out, int out_size, void* d_ws, size_t ws_size,
                              hipStream_t stream) {
  (void)in_sizes; (void)n_in; (void)out_size;
  const int*   tokens  = (const int*)d_in[0];
  const int*   lengths = (const int*)d_in[1];
  const float* emb     = (const float*)d_in[2];
  const float* Wih     = (const float*)d_in[3];
  const float* Whh     = (const float*)d_in[4];
  const float* bih     = (const float*)d_in[5];
  const float* bhh     = (const float*)d_in[6];
  const float* Wfc     = (const float*)d_in[7];
  const float* bfc     = (const float*)d_in[8];
  float* out = (float*)d_out;
  char* ws = (char*)d_ws;

  f16*  h0c  = (f16*)(ws + H0C_OFF);
  u64*  tb0  = (u64*)(ws + T0_OFF);
  u64*  tb1  = (u64*)(ws + T1_OFF);
  float* cbuf = (float*)(ws + C_OFF);
  u32*  rdv  = (u32*)(ws + RDV_OFF);
  f16* emb16 = (f16*)(ws + EMB16_OFF);
  f16* wih16 = (f16*)(ws + WIH16_OFF);
  f16* xp    = (f16*)(ws + XP_OFF);

  int TC = 512;
  while (TC > 64 && (size_t)XP_OFF + (size_t)NB * TC * G4 * 2 > ws_size) TC >>= 1;

  hipLaunchKernelGGL(k0_init, dim3(228), dim3(256), 0, stream, (u32x4*)ws);
  hipLaunchKernelGGL(k_cvt, dim3((NV * HD / 8 + 255) / 256), dim3(256), 0, stream,
                     emb, emb16, NV * HD / 8);
  hipLaunchKernelGGL(k_cvt, dim3((G4 * HD / 8 + 255) / 256), dim3(256), 0, stream,
                     Wih, wih16, G4 * HD / 8);
  for (int t0 = 0; t0 < LMAX; t0 += TC) {
    hipLaunchKernelGGL(k1_xproj, dim3(NB, TC / 64, 16), dim3(256), 0, stream,
                       tokens, lengths, emb16, wih16, bih, bhh, xp, t0, TC);
    hipLaunchKernelGGL(k2_lstm, dim3(256), dim3(256), 0, stream,
                       lengths, Whh, xp, tb0, tb1, h0c, cbuf, rdv, t0 / TC, t0, TC);
  }
  hipLaunchKernelGGL(k3_fc, dim3((NV + 63) / 64), dim3(256), 0, stream,
                     h0c, Wfc, bfc, out);
}

// Round 6
// 2536.169 us; speedup vs baseline: 1.9297x; 1.9297x over previous
//
#include <hip/hip_runtime.h>
#include <stdint.h>

// ---------------------------------------------------------------------------
// LSTMSingle v8 (= v4 transport + latency-path surgery):
//  - Transport: agent-scope IC tagged u64 words {2xf16 h | u32 tag=t+1},
//    fire-and-forget stores, readers spin on tags. (sc0/L2 path falsified
//    in v5-v7: idle-probe fast, loaded-loop limp. Reverted for good.)
//  - Spin waits on TAGS ONLY: no hand vmcnt asm; compiler emits counted
//    vmcnt (tag loads are older than xp loads) so xp stays in flight.
//  - Producer-side gate activation: waves apply sigmoid/tanh in fragment
//    layout before the gS exchange; post-barrier tail = c-update + tanh.
//  - K1: nt loop internal (As tile loaded once, 16 output blocks) -> ~4x
//    less embedding re-fetch.
// ---------------------------------------------------------------------------

#define NB   128
#define LMAX 512
#define HD   512
#define G4   2048
#define NV   50000

// workspace layout (bytes)
#define H0C_OFF     0                            // compact final h [128][512] f16
#define T0_OFF      131072                       // tagged h parity0: 128*256*8
#define T1_OFF      393216                       // tagged h parity1
#define C_OFF       655360                       // c state f32 128*512*4
#define EMB16_OFF   917504
#define EMB16_BYTES (NV * HD * 2)                // 51,200,000
#define WIH16_OFF   (EMB16_OFF + EMB16_BYTES)
#define WIH16_BYTES (G4 * HD * 2)                // 2,097,152
#define XP_OFF      (WIH16_OFF + WIH16_BYTES)
#define INIT_W4     57344                        // 917504/16

typedef _Float16 f16;
typedef _Float16 half8  __attribute__((ext_vector_type(8)));
typedef float    float4v __attribute__((ext_vector_type(4)));
typedef uint32_t u32;
typedef unsigned long long u64;
typedef uint32_t u32x4 __attribute__((ext_vector_type(4)));

__device__ __forceinline__ half8 cvt8(const float* p) {
  float4v a = *(const float4v*)p;
  float4v b = *(const float4v*)(p + 4);
  half8 r;
  r[0] = (f16)a[0]; r[1] = (f16)a[1]; r[2] = (f16)a[2]; r[3] = (f16)a[3];
  r[4] = (f16)b[0]; r[5] = (f16)b[1]; r[6] = (f16)b[2]; r[7] = (f16)b[3];
  return r;
}
__device__ __forceinline__ float sigmoidf_(float x) { return 1.0f / (1.0f + __expf(-x)); }
__device__ __forceinline__ float tanhf_(float x)    { return 1.0f - 2.0f / (1.0f + __expf(2.0f * x)); }

// raw workgroup barrier: LDS visibility only, does NOT drain vmcnt
// (a plain __syncthreads would drain the in-flight xp/tag prefetches)
__device__ __forceinline__ void barx() {
  __builtin_amdgcn_sched_barrier(0);
  __builtin_amdgcn_s_waitcnt(0xC07F);   // lgkmcnt(0), vmcnt/expcnt untouched
  __builtin_amdgcn_s_barrier();
  __builtin_amdgcn_sched_barrier(0);
}

// ---------------------------------------------------------------- K0: init
extern "C" __global__ void k0_init(u32x4* ws4) {
  int idx = blockIdx.x * 256 + threadIdx.x;
  u32x4 z = {0u, 0u, 0u, 0u};
  if (idx < INIT_W4) ws4[idx] = z;
}

// ------------------------------------------------------------- Kcvt: f32->f16
extern "C" __global__ void __launch_bounds__(256)
k_cvt(const float* __restrict__ src, f16* __restrict__ dst, int n8) {
  int i = blockIdx.x * 256 + threadIdx.x;
  if (i >= n8) return;
  ((half8*)dst)[i] = cvt8(src + (size_t)i * 8);
}

// -------------------------------------------------------------- K1: x_proj
// grid (NB, TC/64): As tile loaded ONCE per wg, 16 nt output blocks inside.
extern "C" __global__ void __launch_bounds__(256)
k1_xproj(const int* __restrict__ tokens, const int* __restrict__ lengths,
         const f16* __restrict__ emb16, const f16* __restrict__ wih16,
         const float* __restrict__ bih, const float* __restrict__ bhh,
         f16* __restrict__ xp, int t0c, int TC) {
  int b  = blockIdx.x;
  int mt = blockIdx.y;
  int len = lengths[b];
  int t0 = t0c + mt * 64;
  if (t0 >= len) return;

  __shared__ f16 As[64 * 512];                // 64 KB, XOR-swizzled granules
  int tid = threadIdx.x;

  #pragma unroll
  for (int it = 0; it < 16; ++it) {
    int gl = tid + 256 * it;
    int row = gl >> 6, gi = gl & 63;
    int tok = tokens[b * LMAX + t0 + row];
    half8 v = *(const half8*)(emb16 + (size_t)tok * HD + gi * 8);
    *(half8*)&As[row * 512 + ((gi ^ (row & 7)) * 8)] = v;
  }
  __syncthreads();

  int wave = tid >> 6, lane = tid & 63;
  int quad = lane >> 4, l15 = lane & 15;

  for (int nt = 0; nt < 16; ++nt) {
    int col0 = nt * 128 + wave * 32;

    float4v acc[4][2] = {};
    for (int c = 0; c < 16; ++c) {
      half8 b0 = *(const half8*)(wih16 + (size_t)(col0 + l15) * HD + c * 32 + quad * 8);
      half8 b1 = *(const half8*)(wih16 + (size_t)(col0 + 16 + l15) * HD + c * 32 + quad * 8);
      #pragma unroll
      for (int mm = 0; mm < 4; ++mm) {
        int row = mm * 16 + l15;
        half8 a = *(const half8*)&As[row * 512 + (((c * 4 + quad) ^ (row & 7)) * 8)];
        acc[mm][0] = __builtin_amdgcn_mfma_f32_16x16x32_f16(a, b0, acc[mm][0], 0, 0, 0);
        acc[mm][1] = __builtin_amdgcn_mfma_f32_16x16x32_f16(a, b1, acc[mm][1], 0, 0, 0);
      }
    }

    #pragma unroll
    for (int q = 0; q < 2; ++q) {
      int gcol = col0 + q * 16 + l15;
      float bias = bih[gcol] + bhh[gcol];
      #pragma unroll
      for (int mm = 0; mm < 4; ++mm) {
        #pragma unroll
        for (int j = 0; j < 4; ++j) {
          int t = t0 + mm * 16 + quad * 4 + j;
          if (t < len)
            xp[((size_t)b * TC + (t - t0c)) * G4 + gcol] = (f16)(acc[mm][q][j] + bias);
        }
      }
    }
  }
}

// ---------------------------------------------------------- K2: recurrence
// 128 wgs: group g = wg&7 (16 seqs), memb m = wg>>3 owns h-cols [32m,32m+32).
// One phase per step. Tagged u64 words through IC; readers spin on tags.
extern "C" __global__ void __launch_bounds__(256, 1)
k2_lstm(const int* __restrict__ lengths, const float* __restrict__ Whh,
        const f16* __restrict__ xp, u64* __restrict__ tb0, u64* __restrict__ tb1,
        f16* __restrict__ h0c, float* __restrict__ cbuf, int t0c, int TC) {
  int wg = blockIdx.x;
  int grp = wg & 7, memb = wg >> 3;
  int s0 = grp * 16;
  int tid = threadIdx.x;

  int gm = 0;
  for (int i = 0; i < 16; ++i) { int l = lengths[s0 + i]; gm = l > gm ? l : gm; }
  int tend = (t0c + TC < gm) ? (t0c + TC) : gm;
  if (t0c >= tend) return;

  __shared__ f16 Hs[16 * 512];                 // 16 KB
  __shared__ float gS[16][133];                // padded: odd stride

  int wave = tid >> 6, lane = tid & 63;
  int quad = lane >> 4, l15 = lane & 15;

  // register-resident W_hh fragments: wave w <-> gate w (0:i 1:f 2:g 3:o)
  half8 wf0[16], wf1[16];
  {
    const float* r0 = Whh + (size_t)(wave * 512 + memb * 32 + l15) * HD;
    const float* r1 = r0 + (size_t)16 * HD;
    #pragma unroll
    for (int c = 0; c < 16; ++c) {
      wf0[c] = cvt8(r0 + c * 32 + quad * 8);
      wf1[c] = cvt8(r1 + c * 32 + quad * 8);
    }
  }

  // elementwise: thread owns (seq sE, 2 cols kk0..kk0+1)
  int sE = tid >> 4, kE = tid & 15, kk0 = kE * 2;
  int len = lengths[s0 + sE];
  float c0 = cbuf[(size_t)(s0 + sE) * HD + memb * 32 + kk0];
  float c1 = cbuf[(size_t)(s0 + sE) * HD + memb * 32 + kk0 + 1];

  // own tagged word + initial (frozen) h from previous chunk
  size_t wIdx = (size_t)(s0 + sE) * 256 + memb * 16 + kE;
  const u64* hin0 = (t0c & 1) ? tb1 : tb0;
  u32 hp = (u32)hin0[wIdx];

  // staging address components: thread tid covers col-pair tid of every seq
  int gG = tid >> 2, w4 = (tid & 3) * 2;       // granule 0..63, f16 offset

  u64 a[16];
  #pragma unroll
  for (int r = 0; r < 16; ++r)
    a[r] = __hip_atomic_load(hin0 + (size_t)(s0 + r) * 256 + tid,
                             __ATOMIC_RELAXED, __HIP_MEMORY_SCOPE_AGENT);

  for (int t = t0c; t < tend; ++t) {
    const u64* tin  = (t & 1) ? tb1 : tb0;
    u64*       tout = (t & 1) ? tb0 : tb1;
    u32 tg = (u32)t;

    // xp prefetch in PRODUCER (fragment) layout: issued before the spin so
    // it flies during the wait; spin's compiler-counted vmcnt leaves these
    // (younger) loads outstanding.
    f16 pxa[4], pxb[4];
    {
      const f16* xb = xp + (size_t)(t - t0c) * G4 + wave * 512 + memb * 32 + l15;
      #pragma unroll
      for (int j = 0; j < 4; ++j) {
        size_t off = (size_t)(s0 + quad * 4 + j) * TC * G4;
        pxa[j] = xb[off];
        pxb[j] = xb[off + 16];
      }
    }

    // spin until all 16 tags == t (data+tag atomic in same u64; tags only)
    for (;;) {
      u32 bad = 0;
      #pragma unroll
      for (int r = 0; r < 16; ++r)
        bad |= ((u32)(a[r] >> 32) != tg) ? (1u << r) : 0u;
      if (!bad) break;
      __builtin_amdgcn_s_sleep(1);
      #pragma unroll
      for (int r = 0; r < 16; ++r)
        if (bad & (1u << r))
          a[r] = __hip_atomic_load(tin + (size_t)(s0 + r) * 256 + tid,
                                   __ATOMIC_RELAXED, __HIP_MEMORY_SCOPE_AGENT);
    }

    // stage h into LDS (XOR-swizzled granules)
    #pragma unroll
    for (int r = 0; r < 16; ++r)
      *(u32*)&Hs[r * 512 + ((gG ^ (r & 7)) << 3) + w4] = (u32)a[r];
    barx();

    // GEMM: gates = h @ Whh fragment
    float4v a0e = {}, a0o = {}, a1e = {}, a1o = {};
    #pragma unroll
    for (int c = 0; c < 16; ++c) {
      half8 av = *(const half8*)&Hs[l15 * 512 + (((c * 4 + quad) ^ (l15 & 7)) * 8)];
      if (c & 1) {
        a0o = __builtin_amdgcn_mfma_f32_16x16x32_f16(av, wf0[c], a0o, 0, 0, 0);
        a1o = __builtin_amdgcn_mfma_f32_16x16x32_f16(av, wf1[c], a1o, 0, 0, 0);
      } else {
        a0e = __builtin_amdgcn_mfma_f32_16x16x32_f16(av, wf0[c], a0e, 0, 0, 0);
        a1e = __builtin_amdgcn_mfma_f32_16x16x32_f16(av, wf1[c], a1e, 0, 0, 0);
      }
    }
    float4v g0 = a0e + a0o, g1 = a1e + a1o;

    // producer-side activation: add xp, apply this wave's nonlinearity,
    // publish ACTIVATED gate values to gS.
    #pragma unroll
    for (int j = 0; j < 4; ++j) {
      float v0 = g0[j] + (float)pxa[j];
      float v1 = g1[j] + (float)pxb[j];
      float u0 = (wave == 2) ? tanhf_(v0) : sigmoidf_(v0);
      float u1 = (wave == 2) ? tanhf_(v1) : sigmoidf_(v1);
      gS[quad * 4 + j][wave * 32 + l15]      = u0;
      gS[quad * 4 + j][wave * 32 + 16 + l15] = u1;
    }
    barx();

    // light consumer tail: c-update + output tanh + store
    if (t < len) {
      float i0 = gS[sE][kk0],      i1 = gS[sE][kk0 + 1];
      float f0 = gS[sE][32 + kk0], f1 = gS[sE][32 + kk0 + 1];
      float q0 = gS[sE][64 + kk0], q1 = gS[sE][64 + kk0 + 1];
      float o0 = gS[sE][96 + kk0], o1 = gS[sE][96 + kk0 + 1];
      c0 = f0 * c0 + i0 * q0;
      c1 = f1 * c1 + i1 * q1;
      union { u32 u; f16 h[2]; } hpk;
      hpk.h[0] = (f16)(o0 * tanhf_(c0));
      hpk.h[1] = (f16)(o1 * tanhf_(c1));
      hp = hpk.u;
    }
    u64 wv = ((u64)(u32)(t + 1) << 32) | (u64)hp;
    __hip_atomic_store(tout + wIdx, wv, __ATOMIC_RELAXED, __HIP_MEMORY_SCOPE_AGENT);

    // prefetch next step's words immediately (validated by next spin)
    if (t + 1 < tend) {
      #pragma unroll
      for (int r = 0; r < 16; ++r)
        a[r] = __hip_atomic_load(tout + (size_t)(s0 + r) * 256 + tid,
                                 __ATOMIC_RELAXED, __HIP_MEMORY_SCOPE_AGENT);
    }
  }

  // persist cell state
  cbuf[(size_t)(s0 + sE) * HD + memb * 32 + kk0]     = c0;
  cbuf[(size_t)(s0 + sE) * HD + memb * 32 + kk0 + 1] = c1;

  // compact final h for K3 (frozen values correct for finished seqs)
  *(u32*)&h0c[(size_t)(s0 + sE) * HD + memb * 32 + kk0] = hp;
}

// ----------------------------------------------------------------- K3: FC
extern "C" __global__ void __launch_bounds__(256)
k3_fc(const f16* __restrict__ hT, const float* __restrict__ Wfc,
      const float* __restrict__ bfc, float* __restrict__ out) {
  int tid = threadIdx.x;
  int wave = tid >> 6, lane = tid & 63, quad = lane >> 4, l15 = lane & 15;
  int v = blockIdx.x * 64 + wave * 16 + l15;
  int vc = v < NV ? v : NV - 1;
  float4v acc[8] = {};
  for (int c = 0; c < 16; ++c) {
    half8 bfr = cvt8(Wfc + (size_t)vc * HD + c * 32 + quad * 8);
    #pragma unroll
    for (int mt = 0; mt < 8; ++mt) {
      half8 afr = *(const half8*)&hT[(size_t)(mt * 16 + l15) * HD + c * 32 + quad * 8];
      acc[mt] = __builtin_amdgcn_mfma_f32_16x16x32_f16(afr, bfr, acc[mt], 0, 0, 0);
    }
  }
  if (v < NV) {
    float bias = bfc[v];
    #pragma unroll
    for (int mt = 0; mt < 8; ++mt)
      #pragma unroll
      for (int j = 0; j < 4; ++j)
        out[(size_t)(mt * 16 + quad * 4 + j) * NV + v] = acc[mt][j] + bias;
  }
}

// ---------------------------------------------------------------- launcher
extern "C" void kernel_launch(void* const* d_in, const int* in_sizes, int n_in,
                              void* d_out, int out_size, void* d_ws, size_t ws_size,
                              hipStream_t stream) {
  (void)in_sizes; (void)n_in; (void)out_size;
  const int*   tokens  = (const int*)d_in[0];
  const int*   lengths = (const int*)d_in[1];
  const float* emb     = (const float*)d_in[2];
  const float* Wih     = (const float*)d_in[3];
  const float* Whh     = (const float*)d_in[4];
  const float* bih     = (const float*)d_in[5];
  const float* bhh     = (const float*)d_in[6];
  const float* Wfc     = (const float*)d_in[7];
  const float* bfc     = (const float*)d_in[8];
  float* out = (float*)d_out;
  char* ws = (char*)d_ws;

  f16*  h0c  = (f16*)(ws + H0C_OFF);
  u64*  tb0  = (u64*)(ws + T0_OFF);
  u64*  tb1  = (u64*)(ws + T1_OFF);
  float* cbuf = (float*)(ws + C_OFF);
  f16* emb16 = (f16*)(ws + EMB16_OFF);
  f16* wih16 = (f16*)(ws + WIH16_OFF);
  f16* xp    = (f16*)(ws + XP_OFF);

  int TC = 512;
  while (TC > 64 && (size_t)XP_OFF + (size_t)NB * TC * G4 * 2 > ws_size) TC >>= 1;

  hipLaunchKernelGGL(k0_init, dim3(224), dim3(256), 0, stream, (u32x4*)ws);
  hipLaunchKernelGGL(k_cvt, dim3((NV * HD / 8 + 255) / 256), dim3(256), 0, stream,
                     emb, emb16, NV * HD / 8);
  hipLaunchKernelGGL(k_cvt, dim3((G4 * HD / 8 + 255) / 256), dim3(256), 0, stream,
                     Wih, wih16, G4 * HD / 8);
  for (int t0 = 0; t0 < LMAX; t0 += TC) {
    hipLaunchKernelGGL(k1_xproj, dim3(NB, TC / 64), dim3(256), 0, stream,
                       tokens, lengths, emb16, wih16, bih, bhh, xp, t0, TC);
    hipLaunchKernelGGL(k2_lstm, dim3(128), dim3(256), 0, stream,
                       lengths, Whh, xp, tb0, tb1, h0c, cbuf, t0, TC);
  }
  hipLaunchKernelGGL(k3_fc, dim3((NV + 63) / 64), dim3(256), 0, stream,
                     h0c, Wfc, bfc, out);
}